// Round 5
// baseline (514.947 us; speedup 1.0000x reference)
//
#include <hip/hip_runtime.h>
#include <math.h>

#define Bb 4
#define Tt 2048
#define Cc 1024
#define Hh 16
#define Dd 64
#define QSC 0.18033688011112042f   // (1/sqrt(64)) * log2(e)

typedef unsigned short ushort_t;
typedef __attribute__((ext_vector_type(8))) short short8;
typedef __attribute__((ext_vector_type(4))) float floatx4;

__device__ inline ushort_t f2bf(float x) {
    unsigned int u = __float_as_uint(x);
    return (ushort_t)((u + 0x7FFFu + ((u >> 16) & 1u)) >> 16);
}

// ---------------- x fp32 -> bf16 ----------------
__global__ __launch_bounds__(256) void convert_kernel(
    const float* __restrict__ in, ushort_t* __restrict__ out, int n4)
{
    int i = blockIdx.x * 256 + threadIdx.x;
    if (i < n4) {
        float4 v = *(const float4*)&in[i * 4];
        ushort_t o[4] = {f2bf(v.x), f2bf(v.y), f2bf(v.z), f2bf(v.w)};
        *(uint2*)&out[i * 4] = *(uint2*)o;
    }
}

// ---------------- W [K][N] fp32 -> Wt [N][K] bf16 ----------------
__global__ __launch_bounds__(256) void transpose_kernel(
    const float* __restrict__ W, ushort_t* __restrict__ Wt, int K, int N)
{
    __shared__ ushort_t Ts[16][72];
    const int n0 = blockIdx.x * 64;
    const int k0 = blockIdx.y * 16;
    const int t = threadIdx.x;
#pragma unroll
    for (int i = 0; i < 4; i++) {
        int e = t + i * 256;
        int kl = e >> 6, nl = e & 63;
        Ts[kl][nl] = f2bf(W[(size_t)(k0 + kl) * N + n0 + nl]);
    }
    __syncthreads();
    {
        int nl = t >> 2, kl4 = (t & 3) * 4;
        ushort_t o[4] = {Ts[kl4][nl], Ts[kl4 + 1][nl], Ts[kl4 + 2][nl], Ts[kl4 + 3][nl]};
        *(uint2*)&Wt[(size_t)(n0 + nl) * K + k0 + kl4] = *(uint2*)o;
    }
}

// ---------------- bf16 MFMA GEMM, register-prefetch pipeline ----------------
// 128x128 tile, BK=64. Next K-tile prefetched into VGPRs (plain global loads
// issued BEFORE the MFMA loop), written to LDS after the compute barrier:
// the vmcnt wait gets ~350 cyc of MFMA cover instead of draining pre-barrier.
template <bool OUT_BF16, bool SCALE_Q>
__global__ __launch_bounds__(256) void gemm_bf16_kernel(
    const ushort_t* __restrict__ A, const ushort_t* __restrict__ Bt,
    const float* __restrict__ bias, void* __restrict__ Co,
    int M, int N, int K)
{
    __shared__ __align__(16) ushort_t As[8192];  // frag-linear blocks [(tg,c)]x512
    __shared__ __align__(16) ushort_t Bs[8192];

    const int tid = threadIdx.x;
    const int lane = tid & 63;
    const int w = tid >> 6;
    const int q = lane >> 4;
    const int l = lane & 15;
    const int wm = w >> 1, wn = w & 1;

    const int n0 = blockIdx.x * 128;
    const int m0 = blockIdx.y * 128;

    const ushort_t* Ag = A + (size_t)(m0 + l) * K + q * 8;
    const ushort_t* Bg = Bt + (size_t)(n0 + l) * K + q * 8;

    uint4 pa[2][2], pb[2][2];   // prefetch regs: [t][c]

#define LOADT(k0)                                                              \
    {                                                                          \
        _Pragma("unroll") for (int t = 0; t < 2; t++)                          \
            _Pragma("unroll") for (int c = 0; c < 2; c++) {                    \
                pa[t][c] = *(const uint4*)(Ag + (size_t)(2 * w + t) * 16 * K   \
                                           + (k0) + c * 32);                   \
                pb[t][c] = *(const uint4*)(Bg + (size_t)(2 * w + t) * 16 * K   \
                                           + (k0) + c * 32);                   \
            }                                                                  \
    }
#define STORET()                                                               \
    {                                                                          \
        _Pragma("unroll") for (int t = 0; t < 2; t++)                          \
            _Pragma("unroll") for (int c = 0; c < 2; c++) {                    \
                *(uint4*)&As[((2 * w + t) * 2 + c) * 512 + lane * 8] = pa[t][c];\
                *(uint4*)&Bs[((2 * w + t) * 2 + c) * 512 + lane * 8] = pb[t][c];\
            }                                                                  \
    }

    floatx4 acc[4][4];
#pragma unroll
    for (int i = 0; i < 4; i++)
#pragma unroll
        for (int j = 0; j < 4; j++) acc[i][j] = (floatx4){0.f, 0.f, 0.f, 0.f};

    LOADT(0);
    STORET();
    __syncthreads();

    for (int k0 = 0; k0 < K; k0 += 64) {
        const bool more = (k0 + 64) < K;
        if (more) LOADT(k0 + 64);   // issue early; compute below covers latency

#pragma unroll
        for (int c = 0; c < 2; c++) {
            short8 af[4], bf[4];
#pragma unroll
            for (int mt = 0; mt < 4; mt++)
                af[mt] = *(const short8*)&As[(((wm * 4 + mt) * 2) + c) * 512 + lane * 8];
#pragma unroll
            for (int nt = 0; nt < 4; nt++)
                bf[nt] = *(const short8*)&Bs[(((wn * 4 + nt) * 2) + c) * 512 + lane * 8];
#pragma unroll
            for (int mt = 0; mt < 4; mt++)
#pragma unroll
                for (int nt = 0; nt < 4; nt++)
                    acc[mt][nt] = __builtin_amdgcn_mfma_f32_16x16x32_bf16(
                        af[mt], bf[nt], acc[mt][nt], 0, 0, 0);
        }

        if (more) {
            __syncthreads();   // all waves done reading current tile
            STORET();          // vmcnt wait lands here, after compute cover
            __syncthreads();
        }
    }
#undef LOADT
#undef STORET

    const int rowb = m0 + wm * 64;
    const int colb = n0 + wn * 64;
#pragma unroll
    for (int nt = 0; nt < 4; nt++) {
        const int col = colb + nt * 16 + l;
        const float bi = bias[col];
        const float sc = (SCALE_Q && col < 1024) ? QSC : 1.0f;
#pragma unroll
        for (int mt = 0; mt < 4; mt++) {
#pragma unroll
            for (int r = 0; r < 4; r++) {
                const int row = rowb + mt * 16 + q * 4 + r;
                const float v = (acc[mt][nt][r] + bi) * sc;
                if (OUT_BF16)
                    ((ushort_t*)Co)[(size_t)row * N + col] = f2bf(v);
                else
                    ((float*)Co)[(size_t)row * N + col] = v;
            }
        }
    }
}

// ---------------- bf16 MFMA flash attention, no-max softmax, paired q-tiles ----------------
__global__ __launch_bounds__(256, 2) void attn_mfma_kernel(
    const ushort_t* __restrict__ qkv, ushort_t* __restrict__ yatt)
{
    __shared__ __align__(16) ushort_t Ks[8 * 512];        // frag-linear blocks [nt][kc]
    __shared__ __align__(16) ushort_t Vt[80][80];         // [d][pi(key)], d 64..79 = ones
    __shared__ __align__(16) ushort_t Ps[4][16][80];      // per-wave [q][pi(key)]

    const int tid = threadIdx.x;
    const int lane = tid & 63;
    const int w = tid >> 6;
    const int quad = lane >> 4;
    const int l = lane & 15;

    const int a = blockIdx.x;                  // 0..7
    const int q0h[2] = {a * 128, (15 - a) * 128};
    const int bh = blockIdx.y;
    const int b = bh >> 4;
    const int h = bh & 15;
    const size_t base = (size_t)b * Tt * (3 * Cc);
    const int qoff = h * 64;
    const int koff = Cc + h * 64;
    const int voff = 2 * Cc + h * 64;

    for (int i = tid; i < 16 * 80; i += 256)
        Vt[64 + i / 80][i % 80] = 0x3F80;   // bf16 1.0

    short8 Qf[2][2][2];
#pragma unroll
    for (int hf = 0; hf < 2; hf++)
#pragma unroll
        for (int mt = 0; mt < 2; mt++)
#pragma unroll
            for (int kc = 0; kc < 2; kc++)
                Qf[hf][mt][kc] = *(const short8*)&qkv[base
                    + (size_t)(q0h[hf] + mt * 64 + w * 16 + l) * (3 * Cc)
                    + qoff + kc * 32 + quad * 8];

    floatx4 Oacc[2][2][4];
    floatx4 Lacc[2][2];
#pragma unroll
    for (int hf = 0; hf < 2; hf++)
#pragma unroll
        for (int mt = 0; mt < 2; mt++) {
            Lacc[hf][mt] = (floatx4){0.f, 0.f, 0.f, 0.f};
#pragma unroll
            for (int dt = 0; dt < 4; dt++)
                Oacc[hf][mt][dt] = (floatx4){0.f, 0.f, 0.f, 0.f};
        }

    const int srow = tid >> 2;
    const int sd0 = (tid & 3) * 16;
    const int knt = srow >> 4, kl = srow & 15;
    const int kc_s = sd0 >> 5;
    const int qp0 = (sd0 & 31) >> 3;
    const int pcol = (srow & 15) * 4 + (srow >> 4);

    const int ntil = 32 - 2 * a;
    const int ntil_light = 2 * a + 2;

    for (int kt = 0; kt < ntil; kt++) {
        const int kbase = kt * 64;
        __syncthreads();
        {
            const ushort_t* kp = &qkv[base + (size_t)(kbase + srow) * (3 * Cc) + koff + sd0];
            const ushort_t* vp = &qkv[base + (size_t)(kbase + srow) * (3 * Cc) + voff + sd0];
            uint4 kv0 = *(const uint4*)kp;
            uint4 kv1 = *(const uint4*)(kp + 8);
            *(uint4*)&Ks[(knt * 2 + kc_s) * 512 + (qp0 * 16 + kl) * 8] = kv0;
            *(uint4*)&Ks[(knt * 2 + kc_s) * 512 + ((qp0 + 1) * 16 + kl) * 8] = kv1;
            ushort_t tv[16];
            *(uint4*)&tv[0] = *(const uint4*)vp;
            *(uint4*)&tv[8] = *(const uint4*)(vp + 8);
#pragma unroll
            for (int j = 0; j < 16; j++) Vt[sd0 + j][pcol] = tv[j];
        }
        __syncthreads();

        // K and V fragments hoisted once per k-tile (was per mt-tile: 4x traffic)
        short8 Kf[4][2];
#pragma unroll
        for (int nt = 0; nt < 4; nt++)
#pragma unroll
            for (int kc = 0; kc < 2; kc++)
                Kf[nt][kc] = *(const short8*)&Ks[(nt * 2 + kc) * 512 + lane * 8];
        short8 Vf[5][2];
#pragma unroll
        for (int dt = 0; dt < 5; dt++)
#pragma unroll
            for (int kc = 0; kc < 2; kc++)
                Vf[dt][kc] = *(const short8*)&Vt[dt * 16 + l][kc * 32 + quad * 8];

#pragma unroll
        for (int hf = 0; hf < 2; hf++) {
            if (hf == 0 && kt >= ntil_light) continue;
#pragma unroll
            for (int mt = 0; mt < 2; mt++) {
                const int qmin = q0h[hf] + mt * 64 + (w << 4);
                if (kbase > qmin + 15) continue;

                floatx4 S[4];
#pragma unroll
                for (int nt = 0; nt < 4; nt++) S[nt] = (floatx4){0.f, 0.f, 0.f, 0.f};
#pragma unroll
                for (int kc = 0; kc < 2; kc++)
#pragma unroll
                    for (int nt = 0; nt < 4; nt++)
                        S[nt] = __builtin_amdgcn_mfma_f32_16x16x32_bf16(
                            Qf[hf][mt][kc], Kf[nt][kc], S[nt], 0, 0, 0);

                const bool need_mask = (kbase + 63 > qmin);

#pragma unroll
                for (int r = 0; r < 4; r++) {
                    const int qrow = qmin + quad * 4 + r;
                    float e[4];
#pragma unroll
                    for (int nt = 0; nt < 4; nt++) {
                        float s = S[nt][r];
                        if (need_mask && (kbase + nt * 16 + l > qrow)) s = -INFINITY;
                        e[nt] = __builtin_amdgcn_exp2f(s);
                    }
                    unsigned int u0 = __builtin_amdgcn_perm(
                        __float_as_uint(e[1]), __float_as_uint(e[0]), 0x07060302u);
                    unsigned int u1 = __builtin_amdgcn_perm(
                        __float_as_uint(e[3]), __float_as_uint(e[2]), 0x07060302u);
                    uint2 pk; pk.x = u0; pk.y = u1;
                    *(uint2*)&Ps[w][quad * 4 + r][l * 4] = pk;
                }
                asm volatile("" ::: "memory");

                short8 Pa0 = *(const short8*)&Ps[w][l][quad * 8];
                short8 Pa1 = *(const short8*)&Ps[w][l][32 + quad * 8];
#pragma unroll
                for (int dt = 0; dt < 4; dt++) {
                    Oacc[hf][mt][dt] = __builtin_amdgcn_mfma_f32_16x16x32_bf16(
                        Pa0, Vf[dt][0], Oacc[hf][mt][dt], 0, 0, 0);
                    Oacc[hf][mt][dt] = __builtin_amdgcn_mfma_f32_16x16x32_bf16(
                        Pa1, Vf[dt][1], Oacc[hf][mt][dt], 0, 0, 0);
                }
                Lacc[hf][mt] = __builtin_amdgcn_mfma_f32_16x16x32_bf16(
                    Pa0, Vf[4][0], Lacc[hf][mt], 0, 0, 0);
                Lacc[hf][mt] = __builtin_amdgcn_mfma_f32_16x16x32_bf16(
                    Pa1, Vf[4][1], Lacc[hf][mt], 0, 0, 0);
                asm volatile("" ::: "memory");
            }
        }
    }

#pragma unroll
    for (int hf = 0; hf < 2; hf++)
#pragma unroll
        for (int mt = 0; mt < 2; mt++)
#pragma unroll
            for (int r = 0; r < 4; r++) {
                const float rl = 1.f / Lacc[hf][mt][r];
                const int qrow = q0h[hf] + mt * 64 + (w << 4) + quad * 4 + r;
#pragma unroll
                for (int dt = 0; dt < 4; dt++)
                    yatt[(size_t)(b * Tt + qrow) * Cc + h * 64 + dt * 16 + l] =
                        f2bf(Oacc[hf][mt][dt][r] * rl);
            }
}

extern "C" void kernel_launch(void* const* d_in, const int* in_sizes, int n_in,
                              void* d_out, int out_size, void* d_ws, size_t ws_size,
                              hipStream_t stream) {
    const float* x     = (const float*)d_in[0];
    const float* Wqkv  = (const float*)d_in[1];
    const float* bqkv  = (const float*)d_in[2];
    const float* Wproj = (const float*)d_in[3];
    const float* bproj = (const float*)d_in[4];
    float* out = (float*)d_out;

    ushort_t* qkvb   = (ushort_t*)d_ws;
    ushort_t* yattb  = qkvb + (size_t)8192 * 3072;
    ushort_t* xb     = yattb + (size_t)8192 * 1024;
    ushort_t* wqkvt  = xb + (size_t)8192 * 1024;
    ushort_t* wprojt = wqkvt + (size_t)3072 * 1024;

    convert_kernel<<<(8192 * 1024 / 4 + 255) / 256, 256, 0, stream>>>(x, xb, 8192 * 1024 / 4);
    transpose_kernel<<<dim3(3072 / 64, 1024 / 16), 256, 0, stream>>>(Wqkv, wqkvt, 1024, 3072);
    transpose_kernel<<<dim3(1024 / 64, 1024 / 16), 256, 0, stream>>>(Wproj, wprojt, 1024, 1024);

    gemm_bf16_kernel<true, true><<<dim3(3072 / 128, 8192 / 128), 256, 0, stream>>>(
        xb, wqkvt, bqkv, qkvb, 8192, 3072, 1024);
    attn_mfma_kernel<<<dim3(8, Bb * Hh), 256, 0, stream>>>(qkvb, yattb);
    gemm_bf16_kernel<false, false><<<dim3(1024 / 128, 8192 / 128), 256, 0, stream>>>(
        yattb, wprojt, bproj, out, 8192, 1024, 1024);
}

// Round 6
// 509.448 us; speedup vs baseline: 1.0108x; 1.0108x over previous
//
#include <hip/hip_runtime.h>
#include <math.h>

#define Bb 4
#define Tt 2048
#define Cc 1024
#define Hh 16
#define Dd 64
#define QSC 0.18033688011112042f   // (1/sqrt(64)) * log2(e)

typedef unsigned short ushort_t;
typedef __attribute__((ext_vector_type(8))) short short8;
typedef __attribute__((ext_vector_type(4))) float floatx4;

__device__ inline ushort_t f2bf(float x) {
    unsigned int u = __float_as_uint(x);
    return (ushort_t)((u + 0x7FFFu + ((u >> 16) & 1u)) >> 16);
}

// ---------------- x fp32 -> bf16 ----------------
__global__ __launch_bounds__(256) void convert_kernel(
    const float* __restrict__ in, ushort_t* __restrict__ out, int n4)
{
    int i = blockIdx.x * 256 + threadIdx.x;
    if (i < n4) {
        float4 v = *(const float4*)&in[i * 4];
        ushort_t o[4] = {f2bf(v.x), f2bf(v.y), f2bf(v.z), f2bf(v.w)};
        *(uint2*)&out[i * 4] = *(uint2*)o;
    }
}

// ---------------- W [K][N] fp32 -> Wt [N][K] bf16 ----------------
__global__ __launch_bounds__(256) void transpose_kernel(
    const float* __restrict__ W, ushort_t* __restrict__ Wt, int K, int N)
{
    __shared__ ushort_t Ts[16][72];
    const int n0 = blockIdx.x * 64;
    const int k0 = blockIdx.y * 16;
    const int t = threadIdx.x;
#pragma unroll
    for (int i = 0; i < 4; i++) {
        int e = t + i * 256;
        int kl = e >> 6, nl = e & 63;
        Ts[kl][nl] = f2bf(W[(size_t)(k0 + kl) * N + n0 + nl]);
    }
    __syncthreads();
    {
        int nl = t >> 2, kl4 = (t & 3) * 4;
        ushort_t o[4] = {Ts[kl4][nl], Ts[kl4 + 1][nl], Ts[kl4 + 2][nl], Ts[kl4 + 3][nl]};
        *(uint2*)&Wt[(size_t)(n0 + nl) * K + k0 + kl4] = *(uint2*)o;
    }
}

// ---------------- bf16 MFMA GEMM, register-prefetch pipeline ----------------
// 128x128 tile, BK=64, register prefetch of next K-tile.
// __launch_bounds__(256, 2): 256-VGPR budget -> prefetch regs stay in VGPRs
// (round-5's bare (256) budgeted ~128 VGPR and spilled 440 MB to scratch).
template <bool OUT_BF16, bool SCALE_Q>
__global__ __launch_bounds__(256, 2) void gemm_bf16_kernel(
    const ushort_t* __restrict__ A, const ushort_t* __restrict__ Bt,
    const float* __restrict__ bias, void* __restrict__ Co,
    int M, int N, int K)
{
    __shared__ __align__(16) ushort_t As[8192];  // frag-linear blocks [(tg,c)]x512
    __shared__ __align__(16) ushort_t Bs[8192];

    const int tid = threadIdx.x;
    const int lane = tid & 63;
    const int w = tid >> 6;
    const int q = lane >> 4;
    const int l = lane & 15;
    const int wm = w >> 1, wn = w & 1;

    const int n0 = blockIdx.x * 128;
    const int m0 = blockIdx.y * 128;

    const ushort_t* Ag = A + (size_t)(m0 + l) * K + q * 8;
    const ushort_t* Bg = Bt + (size_t)(n0 + l) * K + q * 8;

    uint4 pa[2][2], pb[2][2];   // prefetch regs: [t][c]

#define LOADT(k0)                                                              \
    {                                                                          \
        _Pragma("unroll") for (int t = 0; t < 2; t++)                          \
            _Pragma("unroll") for (int c = 0; c < 2; c++) {                    \
                pa[t][c] = *(const uint4*)(Ag + (size_t)(2 * w + t) * 16 * K   \
                                           + (k0) + c * 32);                   \
                pb[t][c] = *(const uint4*)(Bg + (size_t)(2 * w + t) * 16 * K   \
                                           + (k0) + c * 32);                   \
            }                                                                  \
    }
#define STORET()                                                               \
    {                                                                          \
        _Pragma("unroll") for (int t = 0; t < 2; t++)                          \
            _Pragma("unroll") for (int c = 0; c < 2; c++) {                    \
                *(uint4*)&As[((2 * w + t) * 2 + c) * 512 + lane * 8] = pa[t][c];\
                *(uint4*)&Bs[((2 * w + t) * 2 + c) * 512 + lane * 8] = pb[t][c];\
            }                                                                  \
    }

    floatx4 acc[4][4];
#pragma unroll
    for (int i = 0; i < 4; i++)
#pragma unroll
        for (int j = 0; j < 4; j++) acc[i][j] = (floatx4){0.f, 0.f, 0.f, 0.f};

    LOADT(0);
    STORET();
    __syncthreads();

    for (int k0 = 0; k0 < K; k0 += 64) {
        const bool more = (k0 + 64) < K;
        if (more) LOADT(k0 + 64);   // issue early; MFMA loop below covers latency

#pragma unroll
        for (int c = 0; c < 2; c++) {
            short8 af[4], bf[4];
#pragma unroll
            for (int mt = 0; mt < 4; mt++)
                af[mt] = *(const short8*)&As[(((wm * 4 + mt) * 2) + c) * 512 + lane * 8];
#pragma unroll
            for (int nt = 0; nt < 4; nt++)
                bf[nt] = *(const short8*)&Bs[(((wn * 4 + nt) * 2) + c) * 512 + lane * 8];
#pragma unroll
            for (int mt = 0; mt < 4; mt++)
#pragma unroll
                for (int nt = 0; nt < 4; nt++)
                    acc[mt][nt] = __builtin_amdgcn_mfma_f32_16x16x32_bf16(
                        af[mt], bf[nt], acc[mt][nt], 0, 0, 0);
        }

        if (more) {
            __syncthreads();   // all waves done reading current tile
            STORET();          // vmcnt wait lands here, after compute cover
            __syncthreads();
        }
    }
#undef LOADT
#undef STORET

    const int rowb = m0 + wm * 64;
    const int colb = n0 + wn * 64;
#pragma unroll
    for (int nt = 0; nt < 4; nt++) {
        const int col = colb + nt * 16 + l;
        const float bi = bias[col];
        const float sc = (SCALE_Q && col < 1024) ? QSC : 1.0f;
#pragma unroll
        for (int mt = 0; mt < 4; mt++) {
#pragma unroll
            for (int r = 0; r < 4; r++) {
                const int row = rowb + mt * 16 + q * 4 + r;
                const float v = (acc[mt][nt][r] + bi) * sc;
                if (OUT_BF16)
                    ((ushort_t*)Co)[(size_t)row * N + col] = f2bf(v);
                else
                    ((float*)Co)[(size_t)row * N + col] = v;
            }
        }
    }
}

// ---------------- bf16 MFMA flash attention, no-max softmax, paired q-tiles ----------------
__global__ __launch_bounds__(256, 2) void attn_mfma_kernel(
    const ushort_t* __restrict__ qkv, ushort_t* __restrict__ yatt)
{
    __shared__ __align__(16) ushort_t Ks[8 * 512];        // frag-linear blocks [nt][kc]
    __shared__ __align__(16) ushort_t Vt[80][80];         // [d][pi(key)], d 64..79 = ones
    __shared__ __align__(16) ushort_t Ps[4][16][80];      // per-wave [q][pi(key)]

    const int tid = threadIdx.x;
    const int lane = tid & 63;
    const int w = tid >> 6;
    const int quad = lane >> 4;
    const int l = lane & 15;

    const int a = blockIdx.x;                  // 0..7
    const int q0h[2] = {a * 128, (15 - a) * 128};
    const int bh = blockIdx.y;
    const int b = bh >> 4;
    const int h = bh & 15;
    const size_t base = (size_t)b * Tt * (3 * Cc);
    const int qoff = h * 64;
    const int koff = Cc + h * 64;
    const int voff = 2 * Cc + h * 64;

    for (int i = tid; i < 16 * 80; i += 256)
        Vt[64 + i / 80][i % 80] = 0x3F80;   // bf16 1.0

    short8 Qf[2][2][2];
#pragma unroll
    for (int hf = 0; hf < 2; hf++)
#pragma unroll
        for (int mt = 0; mt < 2; mt++)
#pragma unroll
            for (int kc = 0; kc < 2; kc++)
                Qf[hf][mt][kc] = *(const short8*)&qkv[base
                    + (size_t)(q0h[hf] + mt * 64 + w * 16 + l) * (3 * Cc)
                    + qoff + kc * 32 + quad * 8];

    floatx4 Oacc[2][2][4];
    floatx4 Lacc[2][2];
#pragma unroll
    for (int hf = 0; hf < 2; hf++)
#pragma unroll
        for (int mt = 0; mt < 2; mt++) {
            Lacc[hf][mt] = (floatx4){0.f, 0.f, 0.f, 0.f};
#pragma unroll
            for (int dt = 0; dt < 4; dt++)
                Oacc[hf][mt][dt] = (floatx4){0.f, 0.f, 0.f, 0.f};
        }

    const int srow = tid >> 2;
    const int sd0 = (tid & 3) * 16;
    const int knt = srow >> 4, kl = srow & 15;
    const int kc_s = sd0 >> 5;
    const int qp0 = (sd0 & 31) >> 3;
    const int pcol = (srow & 15) * 4 + (srow >> 4);

    const int ntil = 32 - 2 * a;
    const int ntil_light = 2 * a + 2;

    for (int kt = 0; kt < ntil; kt++) {
        const int kbase = kt * 64;
        __syncthreads();
        {
            const ushort_t* kp = &qkv[base + (size_t)(kbase + srow) * (3 * Cc) + koff + sd0];
            const ushort_t* vp = &qkv[base + (size_t)(kbase + srow) * (3 * Cc) + voff + sd0];
            uint4 kv0 = *(const uint4*)kp;
            uint4 kv1 = *(const uint4*)(kp + 8);
            *(uint4*)&Ks[(knt * 2 + kc_s) * 512 + (qp0 * 16 + kl) * 8] = kv0;
            *(uint4*)&Ks[(knt * 2 + kc_s) * 512 + ((qp0 + 1) * 16 + kl) * 8] = kv1;
            ushort_t tv[16];
            *(uint4*)&tv[0] = *(const uint4*)vp;
            *(uint4*)&tv[8] = *(const uint4*)(vp + 8);
#pragma unroll
            for (int j = 0; j < 16; j++) Vt[sd0 + j][pcol] = tv[j];
        }
        __syncthreads();

        short8 Kf[4][2];
#pragma unroll
        for (int nt = 0; nt < 4; nt++)
#pragma unroll
            for (int kc = 0; kc < 2; kc++)
                Kf[nt][kc] = *(const short8*)&Ks[(nt * 2 + kc) * 512 + lane * 8];
        short8 Vf[5][2];
#pragma unroll
        for (int dt = 0; dt < 5; dt++)
#pragma unroll
            for (int kc = 0; kc < 2; kc++)
                Vf[dt][kc] = *(const short8*)&Vt[dt * 16 + l][kc * 32 + quad * 8];

#pragma unroll
        for (int hf = 0; hf < 2; hf++) {
            if (hf == 0 && kt >= ntil_light) continue;
#pragma unroll
            for (int mt = 0; mt < 2; mt++) {
                const int qmin = q0h[hf] + mt * 64 + (w << 4);
                if (kbase > qmin + 15) continue;

                floatx4 S[4];
#pragma unroll
                for (int nt = 0; nt < 4; nt++) S[nt] = (floatx4){0.f, 0.f, 0.f, 0.f};
#pragma unroll
                for (int kc = 0; kc < 2; kc++)
#pragma unroll
                    for (int nt = 0; nt < 4; nt++)
                        S[nt] = __builtin_amdgcn_mfma_f32_16x16x32_bf16(
                            Qf[hf][mt][kc], Kf[nt][kc], S[nt], 0, 0, 0);

                const bool need_mask = (kbase + 63 > qmin);

#pragma unroll
                for (int r = 0; r < 4; r++) {
                    const int qrow = qmin + quad * 4 + r;
                    float e[4];
#pragma unroll
                    for (int nt = 0; nt < 4; nt++) {
                        float s = S[nt][r];
                        if (need_mask && (kbase + nt * 16 + l > qrow)) s = -INFINITY;
                        e[nt] = __builtin_amdgcn_exp2f(s);
                    }
                    unsigned int u0 = __builtin_amdgcn_perm(
                        __float_as_uint(e[1]), __float_as_uint(e[0]), 0x07060302u);
                    unsigned int u1 = __builtin_amdgcn_perm(
                        __float_as_uint(e[3]), __float_as_uint(e[2]), 0x07060302u);
                    uint2 pk; pk.x = u0; pk.y = u1;
                    *(uint2*)&Ps[w][quad * 4 + r][l * 4] = pk;
                }
                asm volatile("" ::: "memory");

                short8 Pa0 = *(const short8*)&Ps[w][l][quad * 8];
                short8 Pa1 = *(const short8*)&Ps[w][l][32 + quad * 8];
#pragma unroll
                for (int dt = 0; dt < 4; dt++) {
                    Oacc[hf][mt][dt] = __builtin_amdgcn_mfma_f32_16x16x32_bf16(
                        Pa0, Vf[dt][0], Oacc[hf][mt][dt], 0, 0, 0);
                    Oacc[hf][mt][dt] = __builtin_amdgcn_mfma_f32_16x16x32_bf16(
                        Pa1, Vf[dt][1], Oacc[hf][mt][dt], 0, 0, 0);
                }
                Lacc[hf][mt] = __builtin_amdgcn_mfma_f32_16x16x32_bf16(
                    Pa0, Vf[4][0], Lacc[hf][mt], 0, 0, 0);
                Lacc[hf][mt] = __builtin_amdgcn_mfma_f32_16x16x32_bf16(
                    Pa1, Vf[4][1], Lacc[hf][mt], 0, 0, 0);
                asm volatile("" ::: "memory");
            }
        }
    }

#pragma unroll
    for (int hf = 0; hf < 2; hf++)
#pragma unroll
        for (int mt = 0; mt < 2; mt++)
#pragma unroll
            for (int r = 0; r < 4; r++) {
                const float rl = 1.f / Lacc[hf][mt][r];
                const int qrow = q0h[hf] + mt * 64 + (w << 4) + quad * 4 + r;
#pragma unroll
                for (int dt = 0; dt < 4; dt++)
                    yatt[(size_t)(b * Tt + qrow) * Cc + h * 64 + dt * 16 + l] =
                        f2bf(Oacc[hf][mt][dt][r] * rl);
            }
}

extern "C" void kernel_launch(void* const* d_in, const int* in_sizes, int n_in,
                              void* d_out, int out_size, void* d_ws, size_t ws_size,
                              hipStream_t stream) {
    const float* x     = (const float*)d_in[0];
    const float* Wqkv  = (const float*)d_in[1];
    const float* bqkv  = (const float*)d_in[2];
    const float* Wproj = (const float*)d_in[3];
    const float* bproj = (const float*)d_in[4];
    float* out = (float*)d_out;

    ushort_t* qkvb   = (ushort_t*)d_ws;
    ushort_t* yattb  = qkvb + (size_t)8192 * 3072;
    ushort_t* xb     = yattb + (size_t)8192 * 1024;
    ushort_t* wqkvt  = xb + (size_t)8192 * 1024;
    ushort_t* wprojt = wqkvt + (size_t)3072 * 1024;

    convert_kernel<<<(8192 * 1024 / 4 + 255) / 256, 256, 0, stream>>>(x, xb, 8192 * 1024 / 4);
    transpose_kernel<<<dim3(3072 / 64, 1024 / 16), 256, 0, stream>>>(Wqkv, wqkvt, 1024, 3072);
    transpose_kernel<<<dim3(1024 / 64, 1024 / 16), 256, 0, stream>>>(Wproj, wprojt, 1024, 1024);

    gemm_bf16_kernel<true, true><<<dim3(3072 / 128, 8192 / 128), 256, 0, stream>>>(
        xb, wqkvt, bqkv, qkvb, 8192, 3072, 1024);
    attn_mfma_kernel<<<dim3(8, Bb * Hh), 256, 0, stream>>>(qkvb, yattb);
    gemm_bf16_kernel<false, false><<<dim3(1024 / 128, 8192 / 128), 256, 0, stream>>>(
        yattb, wprojt, bproj, out, 8192, 1024, 1024);
}

// Round 7
// 380.064 us; speedup vs baseline: 1.3549x; 1.3404x over previous
//
#include <hip/hip_runtime.h>
#include <math.h>

#define Bb 4
#define Tt 2048
#define Cc 1024
#define Hh 16
#define Dd 64
#define QSC 0.18033688011112042f   // (1/sqrt(64)) * log2(e)

typedef unsigned short ushort_t;
typedef __attribute__((ext_vector_type(8))) short short8;
typedef __attribute__((ext_vector_type(4))) float floatx4;

typedef unsigned int __attribute__((address_space(1))) u32_as1;
typedef unsigned int __attribute__((address_space(3))) u32_as3;

__device__ __forceinline__ void gld_lds16(const void* g, const void* lds_uniform) {
    // LDS dest = (wave-uniform base) + lane*16 (HW, m104/m108); we pick the
    // per-lane GLOBAL addresses so LDS lands in MFMA fragment order.
    __builtin_amdgcn_global_load_lds(
        (const u32_as1*)(unsigned long long)g,
        (u32_as3*)(unsigned int)(unsigned long long)lds_uniform,
        16, 0, 0);
}

__device__ inline ushort_t f2bf(float x) {
    unsigned int u = __float_as_uint(x);
    return (ushort_t)((u + 0x7FFFu + ((u >> 16) & 1u)) >> 16);
}

// ---------------- x fp32 -> bf16 ----------------
__global__ __launch_bounds__(256) void convert_kernel(
    const float* __restrict__ in, ushort_t* __restrict__ out, int n4)
{
    int i = blockIdx.x * 256 + threadIdx.x;
    if (i < n4) {
        float4 v = *(const float4*)&in[i * 4];
        ushort_t o[4] = {f2bf(v.x), f2bf(v.y), f2bf(v.z), f2bf(v.w)};
        *(uint2*)&out[i * 4] = *(uint2*)o;
    }
}

// ---------------- W [K][N] fp32 -> Wt [N][K] bf16 ----------------
__global__ __launch_bounds__(256) void transpose_kernel(
    const float* __restrict__ W, ushort_t* __restrict__ Wt, int K, int N)
{
    __shared__ ushort_t Ts[16][72];
    const int n0 = blockIdx.x * 64;
    const int k0 = blockIdx.y * 16;
    const int t = threadIdx.x;
#pragma unroll
    for (int i = 0; i < 4; i++) {
        int e = t + i * 256;
        int kl = e >> 6, nl = e & 63;
        Ts[kl][nl] = f2bf(W[(size_t)(k0 + kl) * N + n0 + nl]);
    }
    __syncthreads();
    {
        int nl = t >> 2, kl4 = (t & 3) * 4;
        ushort_t o[4] = {Ts[kl4][nl], Ts[kl4 + 1][nl], Ts[kl4 + 2][nl], Ts[kl4 + 3][nl]};
        *(uint2*)&Wt[(size_t)(n0 + nl) * K + k0 + kl4] = *(uint2*)o;
    }
}

// ---------------- V part of qkv -> Vg[bh][d][pi(key)] bf16 ----------------
// pi within each 64-key tile: col c holds key (c>>2)+(c&3)*16 (matches the
// P-pack column order in the attention kernel).
__global__ __launch_bounds__(256) void vtrans_kernel(
    const ushort_t* __restrict__ qkv, ushort_t* __restrict__ Vg)
{
    __shared__ ushort_t Ts[64][67];
    const int t = threadIdx.x;
    const int kt = blockIdx.x;        // 0..31
    const int bh = blockIdx.y;        // 0..63
    const int b = bh >> 4, h = bh & 15;
    const int kbase = kt * 64;
    const int srow = t >> 2, sd0 = (t & 3) * 16;
    const ushort_t* vp = &qkv[(size_t)b * Tt * 3072
                              + (size_t)(kbase + srow) * 3072 + 2048 + h * 64 + sd0];
    ushort_t tv[16];
    *(uint4*)&tv[0] = *(const uint4*)vp;
    *(uint4*)&tv[8] = *(const uint4*)(vp + 8);
#pragma unroll
    for (int j = 0; j < 16; j++) Ts[sd0 + j][srow] = tv[j];
    __syncthreads();
    const int d = t >> 2, c0 = (t & 3) * 16;
    ushort_t o[16];
#pragma unroll
    for (int i = 0; i < 16; i++) {
        int c = c0 + i;
        o[i] = Ts[d][(c >> 2) + (c & 3) * 16];
    }
    ushort_t* op = &Vg[((size_t)bh * 64 + d) * 2048 + kbase + c0];
    *(uint4*)&op[0] = *(uint4*)&o[0];
    *(uint4*)&op[8] = *(uint4*)&o[8];
}

// ---------------- bf16 MFMA GEMM (round-4 structure: gld_lds, no prefetch) ----------------
template <bool OUT_BF16, bool SCALE_Q>
__global__ __launch_bounds__(256) void gemm_bf16_kernel(
    const ushort_t* __restrict__ A, const ushort_t* __restrict__ Bt,
    const float* __restrict__ bias, void* __restrict__ Co,
    int M, int N, int K)
{
    __shared__ __align__(16) ushort_t As[8192];
    __shared__ __align__(16) ushort_t Bs[8192];

    const int tid = threadIdx.x;
    const int lane = tid & 63;
    const int w = tid >> 6;
    const int q = lane >> 4;
    const int l = lane & 15;
    const int wm = w >> 1, wn = w & 1;

    const int n0 = blockIdx.x * 128;
    const int m0 = blockIdx.y * 128;

    const ushort_t* Ag = A + (size_t)(m0 + l) * K + q * 8;
    const ushort_t* Bg = Bt + (size_t)(n0 + l) * K + q * 8;

    floatx4 acc[4][4];
#pragma unroll
    for (int i = 0; i < 4; i++)
#pragma unroll
        for (int j = 0; j < 4; j++) acc[i][j] = (floatx4){0.f, 0.f, 0.f, 0.f};

    for (int k0 = 0; k0 < K; k0 += 64) {
        __syncthreads();
#pragma unroll
        for (int t = 0; t < 2; t++) {
            const int tg = 2 * w + t;
#pragma unroll
            for (int c = 0; c < 2; c++) {
                gld_lds16(Ag + (size_t)tg * 16 * K + k0 + c * 32, &As[(tg * 2 + c) * 512]);
                gld_lds16(Bg + (size_t)tg * 16 * K + k0 + c * 32, &Bs[(tg * 2 + c) * 512]);
            }
        }
        __syncthreads();

#pragma unroll
        for (int c = 0; c < 2; c++) {
            short8 af[4], bf[4];
#pragma unroll
            for (int mt = 0; mt < 4; mt++)
                af[mt] = *(const short8*)&As[(((wm * 4 + mt) * 2) + c) * 512 + lane * 8];
#pragma unroll
            for (int nt = 0; nt < 4; nt++)
                bf[nt] = *(const short8*)&Bs[(((wn * 4 + nt) * 2) + c) * 512 + lane * 8];
#pragma unroll
            for (int mt = 0; mt < 4; mt++)
#pragma unroll
                for (int nt = 0; nt < 4; nt++)
                    acc[mt][nt] = __builtin_amdgcn_mfma_f32_16x16x32_bf16(
                        af[mt], bf[nt], acc[mt][nt], 0, 0, 0);
        }
    }

    const int rowb = m0 + wm * 64;
    const int colb = n0 + wn * 64;
#pragma unroll
    for (int nt = 0; nt < 4; nt++) {
        const int col = colb + nt * 16 + l;
        const float bi = bias[col];
        const float sc = (SCALE_Q && col < 1024) ? QSC : 1.0f;
#pragma unroll
        for (int mt = 0; mt < 4; mt++) {
#pragma unroll
            for (int r = 0; r < 4; r++) {
                const int row = rowb + mt * 16 + q * 4 + r;
                const float v = (acc[mt][nt][r] + bi) * sc;
                if (OUT_BF16)
                    ((ushort_t*)Co)[(size_t)row * N + col] = f2bf(v);
                else
                    ((float*)Co)[(size_t)row * N + col] = v;
            }
        }
    }
}

// ---------------- bf16 MFMA flash attention ----------------
// One block per (b,h,128-q-rows); heavy-first. All K/V staging via
// global_load_lds into frag-linear LDS (zero-conflict b128 reads). V comes
// pre-transposed+pi-permuted from Vg. Row-sum l via constant ones B-frag.
__global__ __launch_bounds__(256, 2) void attn_mfma_kernel(
    const ushort_t* __restrict__ qkv, const ushort_t* __restrict__ Vg,
    ushort_t* __restrict__ yatt)
{
    __shared__ __align__(16) ushort_t Ks[8 * 512];   // blocks [nt][kc]
    __shared__ __align__(16) ushort_t Vs[8 * 512];   // blocks [dt][kc]
    __shared__ __align__(16) ushort_t Ps[4][16][80]; // per-wave [q][pi(key)]

    const int tid = threadIdx.x;
    const int lane = tid & 63;
    const int w = tid >> 6;
    const int quad = lane >> 4;
    const int l = lane & 15;

    const int qb = 15 - blockIdx.x;            // heavy blocks first
    const int q0 = qb * 128;
    const int bh = blockIdx.y;
    const int b = bh >> 4;
    const int h = bh & 15;
    const size_t base = (size_t)b * Tt * (3 * Cc);
    const int qoff = h * 64;
    const int koff = Cc + h * 64;

    // Q fragments (pre-scaled by QSC in GEMM epilogue)
    short8 Qf[2][2];
#pragma unroll
    for (int mt = 0; mt < 2; mt++)
#pragma unroll
        for (int kc = 0; kc < 2; kc++)
            Qf[mt][kc] = *(const short8*)&qkv[base
                + (size_t)(q0 + mt * 64 + w * 16 + l) * (3 * Cc)
                + qoff + kc * 32 + quad * 8];

    floatx4 Oacc[2][4];
    floatx4 Lacc[2];
#pragma unroll
    for (int mt = 0; mt < 2; mt++) {
        Lacc[mt] = (floatx4){0.f, 0.f, 0.f, 0.f};
#pragma unroll
        for (int dt = 0; dt < 4; dt++)
            Oacc[mt][dt] = (floatx4){0.f, 0.f, 0.f, 0.f};
    }

    const short s1 = (short)0x3F80;   // bf16 1.0
    const short8 ones = {s1, s1, s1, s1, s1, s1, s1, s1};

    // per-lane global staging bases (LDS order = fragment order):
    // K block (nt,kc): lane -> (key = nt*16 + l, d = kc*32 + quad*8)
    const ushort_t* Kg_lane = qkv + base + koff + (size_t)l * (3 * Cc) + quad * 8;
    // V block (dt,kc): lane -> (d = dt*16 + l, picol = kc*32 + quad*8)
    const ushort_t* Vg_lane = Vg + ((size_t)bh * 64 + l) * 2048 + quad * 8;

    const int ntil = 2 * qb + 2;
    for (int kt = 0; kt < ntil; kt++) {
        const int kbase = kt * 64;
        __syncthreads();
        // wave w stages 4 of 16 frag blocks (wave-uniform branch)
#pragma unroll
        for (int i = 0; i < 4; i++) {
            const int idx = w * 4 + i;
            if (idx < 8) {
                const int nt = idx >> 1, kc = idx & 1;
                gld_lds16(Kg_lane + (size_t)(kbase + nt * 16) * (3 * Cc) + kc * 32,
                          &Ks[idx * 512]);
            } else {
                const int dt = (idx - 8) >> 1, kc = idx & 1;
                gld_lds16(Vg_lane + (size_t)(dt * 16) * 2048 + kbase + kc * 32,
                          &Vs[(idx - 8) * 512]);
            }
        }
        __syncthreads();

        short8 Kf[4][2], Vf[4][2];
#pragma unroll
        for (int nt = 0; nt < 4; nt++)
#pragma unroll
            for (int kc = 0; kc < 2; kc++)
                Kf[nt][kc] = *(const short8*)&Ks[(nt * 2 + kc) * 512 + lane * 8];
#pragma unroll
        for (int dt = 0; dt < 4; dt++)
#pragma unroll
            for (int kc = 0; kc < 2; kc++)
                Vf[dt][kc] = *(const short8*)&Vs[(dt * 2 + kc) * 512 + lane * 8];

#pragma unroll
        for (int mt = 0; mt < 2; mt++) {
            const int qmin = q0 + mt * 64 + (w << 4);
            if (kbase > qmin + 15) continue;

            floatx4 S[4];
#pragma unroll
            for (int nt = 0; nt < 4; nt++) S[nt] = (floatx4){0.f, 0.f, 0.f, 0.f};
#pragma unroll
            for (int kc = 0; kc < 2; kc++)
#pragma unroll
                for (int nt = 0; nt < 4; nt++)
                    S[nt] = __builtin_amdgcn_mfma_f32_16x16x32_bf16(
                        Qf[mt][kc], Kf[nt][kc], S[nt], 0, 0, 0);

            const bool need_mask = (kbase + 63 > qmin);

#pragma unroll
            for (int r = 0; r < 4; r++) {
                const int qrow = qmin + quad * 4 + r;
                float e[4];
#pragma unroll
                for (int nt = 0; nt < 4; nt++) {
                    float s = S[nt][r];
                    if (need_mask && (kbase + nt * 16 + l > qrow)) s = -INFINITY;
                    e[nt] = __builtin_amdgcn_exp2f(s);
                }
                unsigned int u0 = __builtin_amdgcn_perm(
                    __float_as_uint(e[1]), __float_as_uint(e[0]), 0x07060302u);
                unsigned int u1 = __builtin_amdgcn_perm(
                    __float_as_uint(e[3]), __float_as_uint(e[2]), 0x07060302u);
                uint2 pk; pk.x = u0; pk.y = u1;
                *(uint2*)&Ps[w][quad * 4 + r][l * 4] = pk;
            }
            asm volatile("" ::: "memory");

            short8 Pa0 = *(const short8*)&Ps[w][l][quad * 8];
            short8 Pa1 = *(const short8*)&Ps[w][l][32 + quad * 8];
#pragma unroll
            for (int dt = 0; dt < 4; dt++) {
                Oacc[mt][dt] = __builtin_amdgcn_mfma_f32_16x16x32_bf16(
                    Pa0, Vf[dt][0], Oacc[mt][dt], 0, 0, 0);
                Oacc[mt][dt] = __builtin_amdgcn_mfma_f32_16x16x32_bf16(
                    Pa1, Vf[dt][1], Oacc[mt][dt], 0, 0, 0);
            }
            Lacc[mt] = __builtin_amdgcn_mfma_f32_16x16x32_bf16(
                Pa0, ones, Lacc[mt], 0, 0, 0);
            Lacc[mt] = __builtin_amdgcn_mfma_f32_16x16x32_bf16(
                Pa1, ones, Lacc[mt], 0, 0, 0);
            asm volatile("" ::: "memory");
        }
    }

#pragma unroll
    for (int mt = 0; mt < 2; mt++)
#pragma unroll
        for (int r = 0; r < 4; r++) {
            const float rl = 1.f / Lacc[mt][r];
            const int qrow = q0 + mt * 64 + (w << 4) + quad * 4 + r;
#pragma unroll
            for (int dt = 0; dt < 4; dt++)
                yatt[(size_t)(b * Tt + qrow) * Cc + h * 64 + dt * 16 + l] =
                    f2bf(Oacc[mt][dt][r] * rl);
        }
}

extern "C" void kernel_launch(void* const* d_in, const int* in_sizes, int n_in,
                              void* d_out, int out_size, void* d_ws, size_t ws_size,
                              hipStream_t stream) {
    const float* x     = (const float*)d_in[0];
    const float* Wqkv  = (const float*)d_in[1];
    const float* bqkv  = (const float*)d_in[2];
    const float* Wproj = (const float*)d_in[3];
    const float* bproj = (const float*)d_in[4];
    float* out = (float*)d_out;

    ushort_t* qkvb   = (ushort_t*)d_ws;                 // 48 MB
    ushort_t* yattb  = qkvb + (size_t)8192 * 3072;      // 16 MB
    ushort_t* xb     = yattb + (size_t)8192 * 1024;     // 16 MB
    ushort_t* wqkvt  = xb + (size_t)8192 * 1024;        // 6 MB
    ushort_t* wprojt = wqkvt + (size_t)3072 * 1024;     // 2 MB
    ushort_t* vg     = wprojt + (size_t)1024 * 1024;    // 16 MB

    convert_kernel<<<(8192 * 1024 / 4 + 255) / 256, 256, 0, stream>>>(x, xb, 8192 * 1024 / 4);
    transpose_kernel<<<dim3(3072 / 64, 1024 / 16), 256, 0, stream>>>(Wqkv, wqkvt, 1024, 3072);
    transpose_kernel<<<dim3(1024 / 64, 1024 / 16), 256, 0, stream>>>(Wproj, wprojt, 1024, 1024);

    gemm_bf16_kernel<true, true><<<dim3(3072 / 128, 8192 / 128), 256, 0, stream>>>(
        xb, wqkvt, bqkv, qkvb, 8192, 3072, 1024);
    vtrans_kernel<<<dim3(Tt / 64, Bb * Hh), 256, 0, stream>>>(qkvb, vg);
    attn_mfma_kernel<<<dim3(16, Bb * Hh), 256, 0, stream>>>(qkvb, vg, yattb);
    gemm_bf16_kernel<false, false><<<dim3(1024 / 128, 8192 / 128), 256, 0, stream>>>(
        yattb, wprojt, bproj, out, 8192, 1024, 1024);
}